// Round 5
// baseline (331.843 us; speedup 1.0000x reference)
//
#include <hip/hip_runtime.h>
#include <hip/hip_bf16.h>
#include <math.h>

typedef __bf16 bf16_t;
typedef __bf16 bf16x8 __attribute__((ext_vector_type(8)));
typedef float  f32x4  __attribute__((ext_vector_type(4)));
typedef float  f32x16 __attribute__((ext_vector_type(16)));

#define BB 8
#define CC 128
#define NN 4096
#define LDP 136
// 1/sqrt(128) * log2(e)  (attention scale folded into q, softmax in exp2 domain)
#define SCALE2 0.12751743342f

static __device__ __forceinline__ f32x4 mfma16(bf16x8 a, bf16x8 b, f32x4 c) {
    return __builtin_amdgcn_mfma_f32_16x16x32_bf16(a, b, c, 0, 0, 0);
}
static __device__ __forceinline__ f32x16 mfma32(bf16x8 a, bf16x8 b, f32x16 c) {
    return __builtin_amdgcn_mfma_f32_32x32x16_bf16(a, b, c, 0, 0, 0);
}
static __device__ __forceinline__ void gld16(const void* g, void* l) {
    __builtin_amdgcn_global_load_lds(
        (const __attribute__((address_space(1))) void*)g,
        (__attribute__((address_space(3))) void*)l, 16, 0, 0);
}
static __device__ __forceinline__ unsigned pack2bf(float a, float b) {
    union { bf16_t h[2]; unsigned u; } r;
    r.h[0] = (bf16_t)a; r.h[1] = (bf16_t)b;
    return r.u;
}

// ---------------- K1a: GroupNorm stats ----------------
__global__ void __launch_bounds__(256) gn_stats(const float* __restrict__ in,
                                                float* __restrict__ stats) {
    int bg = blockIdx.x;
    const float4* p4 = (const float4*)(in + (size_t)bg * 16384);
    int tid = threadIdx.x;
    float s = 0.f, ss = 0.f;
    for (int i = tid; i < 4096; i += 256) {
        float4 v = p4[i];
        s  += v.x + v.y + v.z + v.w;
        ss += v.x*v.x + v.y*v.y + v.z*v.z + v.w*v.w;
    }
    for (int off = 1; off < 64; off <<= 1) {
        s  += __shfl_xor(s,  off, 64);
        ss += __shfl_xor(ss, off, 64);
    }
    __shared__ float red[8];
    int wv = tid >> 6;
    if ((tid & 63) == 0) { red[wv*2] = s; red[wv*2+1] = ss; }
    __syncthreads();
    if (tid == 0) {
        float S  = red[0]+red[2]+red[4]+red[6];
        float SS = red[1]+red[3]+red[5]+red[7];
        float mu  = S * (1.f/16384.f);
        float var = SS * (1.f/16384.f) - mu*mu;
        stats[bg*2]   = mu;
        stats[bg*2+1] = rsqrtf(var + 1e-5f);
    }
}

// ---------------- K1b: normalize -> d_out (fp32) + x tokens (bf16 [B,N,C]) ----------------
__global__ void __launch_bounds__(256) gn_apply(const float* __restrict__ in,
                                                const float* __restrict__ gw,
                                                const float* __restrict__ gb,
                                                const float* __restrict__ stats,
                                                float* __restrict__ normed,
                                                bf16_t* __restrict__ x) {
    int b  = blockIdx.x >> 6;
    int p0 = (blockIdx.x & 63) << 6;
    int tid = threadIdx.x;
    __shared__ bf16_t tile[64 * 130];
    for (int i = tid; i < 8192; i += 256) {
        int c = i >> 6, p = i & 63;
        size_t idx = ((size_t)(b*CC + c)) * NN + p0 + p;
        float v = in[idx];
        int sg = b*32 + (c >> 2);
        float xn = (v - stats[sg*2]) * stats[sg*2+1] * gw[c] + gb[c];
        normed[idx] = xn;
        tile[p*130 + c] = (bf16_t)xn;
    }
    __syncthreads();
    bf16_t* xb = x + ((size_t)(b*NN + p0)) * CC;
    for (int i = tid; i < 4096; i += 256) {
        int p = i >> 6, cp = i & 63;
        unsigned int d = *(const unsigned int*)&tile[p*130 + cp*2];
        *(unsigned int*)&xb[p*CC + cp*2] = d;
    }
}

// ---------------- K2: phase-parallel qkv. grid 768: ph = blk>>8 ----------------
// q plain+scaled; k XOR-swizzled; vT transposed + bit2<->3 j-perm + XOR-swizzled.
__global__ void __launch_bounds__(256) qkv_gemm(const bf16_t* __restrict__ x,
        const float* __restrict__ Wq, const float* __restrict__ bq,
        const float* __restrict__ Wk, const float* __restrict__ bk,
        const float* __restrict__ Wv, const float* __restrict__ bv,
        bf16_t* __restrict__ q, bf16_t* __restrict__ k, bf16_t* __restrict__ vT) {
    __shared__ bf16_t wb[CC * LDP];
    const int ph  = blockIdx.x >> 8;
    const int blk = blockIdx.x & 255;
    int b  = blk >> 5;
    int n0 = (blk & 31) << 7;
    int tid = threadIdx.x;
    int lane = tid & 63, l15 = lane & 15, quad = lane >> 4;
    int w = tid >> 6;
    bf16x8 afr[2][4];
    #pragma unroll
    for (int rt = 0; rt < 2; rt++)
        #pragma unroll
        for (int kb = 0; kb < 4; kb++)
            afr[rt][kb] = *(const bf16x8*)&x[(size_t)(b*NN + n0 + w*32 + rt*16 + l15)*CC + kb*32 + quad*8];

    const float* W  = (ph == 0) ? Wq : (ph == 1 ? Wk : Wv);
    const float* bs = (ph == 0) ? bq : (ph == 1 ? bk : bv);
    for (int i = tid; i < 2048; i += 256) {
        int row = i >> 4, s8 = i & 15;
        const float* wp = W + row*128 + s8*8;
        bf16x8 v;
        #pragma unroll
        for (int j = 0; j < 8; j++) v[j] = (bf16_t)wp[j];
        *(bf16x8*)&wb[row*LDP + s8*8] = v;
    }
    __syncthreads();
    f32x4 acc[2][8];
    f32x4 z = {0.f, 0.f, 0.f, 0.f};
    #pragma unroll
    for (int rt = 0; rt < 2; rt++)
        #pragma unroll
        for (int t = 0; t < 8; t++) acc[rt][t] = z;
    #pragma unroll
    for (int kb = 0; kb < 4; kb++)
        #pragma unroll
        for (int t = 0; t < 8; t++) {
            bf16x8 bf = *(const bf16x8*)&wb[(t*16 + l15)*LDP + kb*32 + quad*8];
            acc[0][t] = mfma16(afr[0][kb], bf, acc[0][t]);
            acc[1][t] = mfma16(afr[1][kb], bf, acc[1][t]);
        }
    __syncthreads();   // all waves done reading W from wb
    if (ph < 2) {
        float sc = (ph == 0) ? SCALE2 : 1.0f;
        #pragma unroll
        for (int t = 0; t < 8; t++) {
            float bias = bs[t*16 + l15];
            #pragma unroll
            for (int rt = 0; rt < 2; rt++)
                #pragma unroll
                for (int r = 0; r < 4; r++) {
                    int nloc = w*32 + rt*16 + quad*4 + r;
                    wb[nloc*LDP + t*16 + l15] = (bf16_t)((acc[rt][t][r] + bias) * sc);
                }
        }
        __syncthreads();
        bf16_t* outp = (ph == 0) ? q : k;
        for (int i = tid; i < 2048; i += 256) {
            int row = i >> 4, g = i & 15;
            bf16x8 vv = *(const bf16x8*)&wb[row*LDP + g*8];
            int gd = (ph == 0) ? g : (g ^ (row & 15));
            *(bf16x8*)&outp[(size_t)(b*NN + n0 + row)*CC + gd*8] = vv;
        }
    } else {
        #pragma unroll
        for (int t = 0; t < 8; t++) {
            float bias = bs[t*16 + l15];
            #pragma unroll
            for (int rt = 0; rt < 2; rt++)
                #pragma unroll
                for (int r = 0; r < 4; r++) {
                    int nloc = w*32 + rt*16 + quad*4 + r;   // vT transpose: [c][nloc]
                    wb[(t*16 + l15)*LDP + nloc] = (bf16_t)(acc[rt][t][r] + bias);
                }
        }
        __syncthreads();
        for (int i = tid; i < 8192; i += 256) {
            int c = i >> 6, np = i & 63;   // np = pair index (n = 2*np)
            unsigned int d = *(const unsigned int*)&wb[c*LDP + np*2];
            // bit2<->3 swap of n == bit1<->2 swap of np (PV B-frag identity perm)
            int npp = (np & ~6) | ((np & 2) << 1) | ((np & 4) >> 1);
            int g = (npp >> 2) ^ (c & 15);            // XOR bank swizzle on 8-elem groups
            *(unsigned int*)&vT[(size_t)(b*CC + c)*NN + n0 + (g << 3) + ((npp & 3) << 1)] = d;
        }
    }
}

// ---------------- K3: flash, 512 thr (2 waves/SIMD), maxless tt-streamed softmax ----------------
// grid 256: b = blk>>5, qb = (blk>>2)&7 (512 q-rows), jq = blk&3 (1024 j).
// Partials: packed bf16 pairs opd[jq][b][cpair][q] + l sums mlf[jq][b][q].
__global__ void __launch_bounds__(512, 2) flash_attn(const bf16_t* __restrict__ qg_,
                                                     const bf16_t* __restrict__ kg,
                                                     const bf16_t* __restrict__ vg,
                                                     unsigned* __restrict__ opd,
                                                     float* __restrict__ mlf) {
    __shared__ bf16_t kbuf[2][128*128];   // 64 KB
    __shared__ bf16_t vbuf[2][128*128];   // 64 KB
    const int b    = blockIdx.x >> 5;
    const int qb   = (blockIdx.x >> 2) & 7;
    const int jq   = blockIdx.x & 3;
    const int q0   = qb << 9;
    const int j00  = jq << 10;
    const int tid  = threadIdx.x;
    const int lane = tid & 63;
    const int l31  = lane & 31;
    const int h    = lane >> 5;
    const int w    = tid >> 6;            // 0..7

    const bf16_t* qr0 = qg_ + ((size_t)(b*NN + q0 + w*64 + l31))*CC + h*8;
    const bf16_t* qr1 = qr0 + 32*CC;
    bf16x8 qf0[8];                        // group-0 q frags resident
    #pragma unroll
    for (int kc = 0; kc < 8; kc++) qf0[kc] = *(const bf16x8*)(qr0 + kc*16);

    int gofs[8];
    #pragma unroll
    for (int kc = 0; kc < 8; kc++) gofs[kc] = ((2*kc + h) ^ (l31 & 15)) << 3;

    f32x16 ot0[4], ot1[4];
    #pragma unroll
    for (int ct = 0; ct < 4; ct++)
        #pragma unroll
        for (int r = 0; r < 16; r++) { ot0[ct][r] = 0.f; ot1[ct][r] = 0.f; }
    float l0 = 0.f, l1 = 0.f;

    // stage tile 0
    {
        const bf16_t* kt = kg + ((size_t)(b*NN + j00))*CC;
        #pragma unroll
        for (int it = 0; it < 4; it++) {
            int cb = it*512 + w*64;
            gld16(kt + (size_t)(cb + lane)*8, &kbuf[0][cb*8]);
        }
        #pragma unroll
        for (int it = 0; it < 4; it++) {
            int cb = it*512 + w*64;
            int c = cb + lane;
            gld16(vg + ((size_t)(b*CC + (c >> 4)))*NN + j00 + (c & 15)*8, &vbuf[0][cb*8]);
        }
    }
    __syncthreads();

    for (int i = 0; i < 8; i++) {
        const int cur = i & 1;
        if (i < 7) {                       // prefetch next tile (drained by end barrier)
            const int j0n = j00 + ((i + 1) << 7);
            const bf16_t* kt = kg + ((size_t)(b*NN + j0n))*CC;
            #pragma unroll
            for (int it = 0; it < 4; it++) {
                int cb = it*512 + w*64;
                gld16(kt + (size_t)(cb + lane)*8, &kbuf[cur^1][cb*8]);
            }
            #pragma unroll
            for (int it = 0; it < 4; it++) {
                int cb = it*512 + w*64;
                int c = cb + lane;
                gld16(vg + ((size_t)(b*CC + (c >> 4)))*NN + j0n + (c & 15)*8, &vbuf[cur^1][cb*8]);
            }
        }
        // group-1 q frags reloaded per iter (keeps peak VGPR under 256)
        bf16x8 qf1[8];
        #pragma unroll
        for (int kc = 0; kc < 8; kc++) qf1[kc] = *(const bf16x8*)(qr1 + kc*16);

        #pragma unroll
        for (int tt = 0; tt < 4; tt++) {
            // S^T chunk (32 j-rows) for both q-groups; kf reuse = 2
            f32x16 st0, st1;
            #pragma unroll
            for (int r = 0; r < 16; r++) { st0[r] = 0.f; st1[r] = 0.f; }
            const bf16_t* krow = &kbuf[cur][(tt*32 + l31)*128];
            #pragma unroll
            for (int kc = 0; kc < 8; kc++) {
                bf16x8 kf = *(const bf16x8*)(krow + gofs[kc]);
                st0 = mfma32(kf, qf0[kc], st0);
                st1 = mfma32(kf, qf1[kc], st1);
            }
            // maxless softmax: exp2 (independent), tree sums, pack
            #pragma unroll
            for (int r = 0; r < 16; r++) st0[r] = __builtin_amdgcn_exp2f(st0[r]);
            #pragma unroll
            for (int r = 0; r < 16; r++) st1[r] = __builtin_amdgcn_exp2f(st1[r]);
            {
                float a0 = (st0[0]+st0[1]) + (st0[2]+st0[3]);
                float a1 = (st0[4]+st0[5]) + (st0[6]+st0[7]);
                float a2 = (st0[8]+st0[9]) + (st0[10]+st0[11]);
                float a3 = (st0[12]+st0[13]) + (st0[14]+st0[15]);
                l0 += (a0 + a1) + (a2 + a3);
                float c0 = (st1[0]+st1[1]) + (st1[2]+st1[3]);
                float c1 = (st1[4]+st1[5]) + (st1[6]+st1[7]);
                float c2 = (st1[8]+st1[9]) + (st1[10]+st1[11]);
                float c3 = (st1[12]+st1[13]) + (st1[14]+st1[15]);
                l1 += (c0 + c1) + (c2 + c3);
            }
            union { unsigned u[4]; bf16x8 v; } pf0[2], pf1[2];
            #pragma unroll
            for (int kcl = 0; kcl < 2; kcl++)
                #pragma unroll
                for (int g = 0; g < 4; g++) {
                    pf0[kcl].u[g] = pack2bf(st0[8*kcl + 2*g], st0[8*kcl + 2*g + 1]);
                    pf1[kcl].u[g] = pack2bf(st1[8*kcl + 2*g], st1[8*kcl + 2*g + 1]);
                }
            // PV for this j-chunk; vf reuse = 2; pure accumulate (no rescale)
            #pragma unroll
            for (int kcl = 0; kcl < 2; kcl++) {
                const int kc = tt*2 + kcl;
                #pragma unroll
                for (int ct = 0; ct < 4; ct++) {
                    bf16x8 vf = *(const bf16x8*)&vbuf[cur][(ct*32 + l31)*128 + gofs[kc]];
                    ot0[ct] = mfma32(vf, pf0[kcl].v, ot0[ct]);
                    ot1[ct] = mfma32(vf, pf1[kcl].v, ot1[ct]);
                }
            }
        }
        __syncthreads();
    }
    // epilogue: combine lane^32 halves of l; store packed bf16 partials [cpair][q]
    l0 += __shfl_xor(l0, 32, 64);
    l1 += __shfl_xor(l1, 32, 64);
    const int row0 = q0 + w*64 + l31;
    unsigned* ob = opd + ((size_t)(jq*BB + b)) * 64 * NN;
    #pragma unroll
    for (int ct = 0; ct < 4; ct++)
        #pragma unroll
        for (int rp = 0; rp < 8; rp++) {
            int cpair = ct*16 + (rp & 1) + 4*(rp >> 1) + 2*h;
            ob[(size_t)cpair*NN + row0]      = pack2bf(ot0[ct][2*rp], ot0[ct][2*rp + 1]);
            ob[(size_t)cpair*NN + row0 + 32] = pack2bf(ot1[ct][2*rp], ot1[ct][2*rp + 1]);
        }
    if (h == 0) {
        float* mlp = mlf + ((size_t)(jq*BB + b)) * NN;
        mlp[row0]      = l0;
        mlp[row0 + 32] = l1;
    }
}

// ---------------- K3b: merge 4 j-quarter partials (plain sums) -> ao (bf16 [B,N,C]) ----------------
__global__ void __launch_bounds__(256) merge_attn(const unsigned* __restrict__ opd,
                                                  const float* __restrict__ mlf,
                                                  bf16_t* __restrict__ ao) {
    __shared__ float inv[128];
    __shared__ unsigned tile[128 * 65];
    const int b  = blockIdx.x >> 5;
    const int q0 = (blockIdx.x & 31) << 7;
    const int tid = threadIdx.x;
    if (tid < 128) {
        float lt = 0.f;
        #pragma unroll
        for (int p = 0; p < 4; p++) lt += mlf[((size_t)(p*BB + b))*NN + q0 + tid];
        inv[tid] = 1.0f / lt;
    }
    __syncthreads();
    for (int i = tid; i < 8192; i += 256) {
        int q = i & 127, cp = i >> 7;
        float lo = 0.f, hi = 0.f;
        #pragma unroll
        for (int p = 0; p < 4; p++) {
            unsigned u = opd[(((size_t)(p*BB + b))*64 + cp)*NN + q0 + q];
            union { unsigned u; float f; } a, c;
            a.u = u << 16; c.u = u & 0xffff0000u;
            lo += a.f; hi += c.f;
        }
        float s = inv[q];
        tile[q*65 + cp] = pack2bf(lo * s, hi * s);
    }
    __syncthreads();
    unsigned* aod = (unsigned*)ao;
    for (int i = tid; i < 8192; i += 256) {
        int q = i >> 6, cp = i & 63;
        aod[((size_t)(b*NN + q0 + q))*64 + cp] = tile[q*65 + cp];
    }
}

// ---------------- K4: proj GEMM + bias + transpose + residual into d_out ----------------
__global__ void __launch_bounds__(256) proj_out(const bf16_t* __restrict__ ao,
                                                const float* __restrict__ Wp,
                                                const float* __restrict__ bp,
                                                float* __restrict__ out) {
    __shared__ bf16_t wb[CC * LDP];
    int b  = blockIdx.x >> 5;
    int n0 = (blockIdx.x & 31) << 7;
    int tid = threadIdx.x;
    int lane = tid & 63, l15 = lane & 15, quad = lane >> 4;
    int w = tid >> 6;
    bf16x8 afr[2][4];
    #pragma unroll
    for (int rt = 0; rt < 2; rt++)
        #pragma unroll
        for (int kb = 0; kb < 4; kb++)
            afr[rt][kb] = *(const bf16x8*)&ao[(size_t)(b*NN + n0 + w*32 + rt*16 + l15)*CC + kb*32 + quad*8];
    for (int i = tid; i < 2048; i += 256) {
        int row = i >> 4, s8 = i & 15;
        const float* wp = Wp + row*128 + s8*8;
        bf16x8 v;
        #pragma unroll
        for (int j = 0; j < 8; j++) v[j] = (bf16_t)wp[j];
        *(bf16x8*)&wb[row*LDP + s8*8] = v;
    }
    __syncthreads();
    f32x4 acc[2][8];
    f32x4 z = {0.f, 0.f, 0.f, 0.f};
    #pragma unroll
    for (int rt = 0; rt < 2; rt++)
        #pragma unroll
        for (int t = 0; t < 8; t++) acc[rt][t] = z;
    #pragma unroll
    for (int kb = 0; kb < 4; kb++)
        #pragma unroll
        for (int t = 0; t < 8; t++) {
            bf16x8 bf = *(const bf16x8*)&wb[(t*16 + l15)*LDP + kb*32 + quad*8];
            acc[0][t] = mfma16(afr[0][kb], bf, acc[0][t]);
            acc[1][t] = mfma16(afr[1][kb], bf, acc[1][t]);
        }
    __syncthreads();
    #pragma unroll
    for (int t = 0; t < 8; t++) {
        float bias = bp[t*16 + l15];
        #pragma unroll
        for (int rt = 0; rt < 2; rt++)
            #pragma unroll
            for (int r = 0; r < 4; r++) {
                int nloc = w*32 + rt*16 + quad*4 + r;
                wb[(t*16 + l15)*LDP + nloc] = (bf16_t)(acc[rt][t][r] + bias);
            }
    }
    __syncthreads();
    for (int i = tid; i < 8192; i += 256) {
        int c = i >> 6, np = i & 63;
        bf16_t b0 = wb[c*LDP + np*2], b1 = wb[c*LDP + np*2 + 1];
        size_t idx = (size_t)(b*CC + c)*NN + n0 + np*2;
        float2 nv = *(float2*)&out[idx];
        nv.x += (float)b0;
        nv.y += (float)b1;
        *(float2*)&out[idx] = nv;
    }
}

extern "C" void kernel_launch(void* const* d_in, const int* in_sizes, int n_in,
                              void* d_out, int out_size, void* d_ws, size_t ws_size,
                              hipStream_t stream) {
    const float* in = (const float*)d_in[0];
    const float* gw = (const float*)d_in[1];
    const float* gb = (const float*)d_in[2];
    const float* Wq = (const float*)d_in[3];
    const float* bq = (const float*)d_in[4];
    const float* Wk = (const float*)d_in[5];
    const float* bk = (const float*)d_in[6];
    const float* Wv = (const float*)d_in[7];
    const float* bv = (const float*)d_in[8];
    const float* Wp = (const float*)d_in[9];
    const float* bp = (const float*)d_in[10];
    float* out = (float*)d_out;

    char* ws = (char*)d_ws;
    const size_t SZ = (size_t)BB * NN * CC * 2;        // 8.39 MB
    float*    stats = (float*)ws;
    bf16_t*   x  = (bf16_t*)(ws + 2048);
    bf16_t*   q  = (bf16_t*)(ws + 2048 + SZ);
    bf16_t*   kk = (bf16_t*)(ws + 2048 + 2*SZ);
    bf16_t*   vT = (bf16_t*)(ws + 2048 + 3*SZ);
    bf16_t*   ao = (bf16_t*)(ws + 2048 + 4*SZ);
    unsigned* op = (unsigned*)(ws + 2048 + 5*SZ);      // 33.55 MB packed-bf16 partials
    float*    ml = (float*)(ws + 2048 + 5*SZ + (size_t)4*BB*64*NN*4);

    gn_stats  <<<256, 256, 0, stream>>>(in, stats);
    gn_apply  <<<512, 256, 0, stream>>>(in, gw, gb, stats, out, x);
    qkv_gemm  <<<768, 256, 0, stream>>>(x, Wq, bq, Wk, bk, Wv, bv, q, kk, vT);
    flash_attn<<<256, 512, 0, stream>>>(q, kk, vT, op, ml);
    merge_attn<<<256, 256, 0, stream>>>(op, ml, ao);
    proj_out  <<<256, 256, 0, stream>>>(ao, Wp, bp, out);
}

// Round 6
// 201.576 us; speedup vs baseline: 1.6462x; 1.6462x over previous
//
#include <hip/hip_runtime.h>
#include <hip/hip_bf16.h>
#include <math.h>

typedef __bf16 bf16_t;
typedef __bf16 bf16x8 __attribute__((ext_vector_type(8)));
typedef float  f32x4  __attribute__((ext_vector_type(4)));
typedef float  f32x16 __attribute__((ext_vector_type(16)));

#define BB 8
#define CC 128
#define NN 4096
#define LDP 136
// 1/sqrt(128) * log2(e)  (attention scale folded into q, softmax in exp2 domain)
#define SCALE2 0.12751743342f

static __device__ __forceinline__ f32x4 mfma16(bf16x8 a, bf16x8 b, f32x4 c) {
    return __builtin_amdgcn_mfma_f32_16x16x32_bf16(a, b, c, 0, 0, 0);
}
static __device__ __forceinline__ f32x16 mfma32(bf16x8 a, bf16x8 b, f32x16 c) {
    return __builtin_amdgcn_mfma_f32_32x32x16_bf16(a, b, c, 0, 0, 0);
}
static __device__ __forceinline__ void gld16(const void* g, void* l) {
    __builtin_amdgcn_global_load_lds(
        (const __attribute__((address_space(1))) void*)g,
        (__attribute__((address_space(3))) void*)l, 16, 0, 0);
}
static __device__ __forceinline__ unsigned pack2bf(float a, float b) {
    union { bf16_t h[2]; unsigned u; } r;
    r.h[0] = (bf16_t)a; r.h[1] = (bf16_t)b;
    return r.u;
}

// ---------------- K1a: GroupNorm stats ----------------
__global__ void __launch_bounds__(256) gn_stats(const float* __restrict__ in,
                                                float* __restrict__ stats) {
    int bg = blockIdx.x;
    const float4* p4 = (const float4*)(in + (size_t)bg * 16384);
    int tid = threadIdx.x;
    float s = 0.f, ss = 0.f;
    for (int i = tid; i < 4096; i += 256) {
        float4 v = p4[i];
        s  += v.x + v.y + v.z + v.w;
        ss += v.x*v.x + v.y*v.y + v.z*v.z + v.w*v.w;
    }
    for (int off = 1; off < 64; off <<= 1) {
        s  += __shfl_xor(s,  off, 64);
        ss += __shfl_xor(ss, off, 64);
    }
    __shared__ float red[8];
    int wv = tid >> 6;
    if ((tid & 63) == 0) { red[wv*2] = s; red[wv*2+1] = ss; }
    __syncthreads();
    if (tid == 0) {
        float S  = red[0]+red[2]+red[4]+red[6];
        float SS = red[1]+red[3]+red[5]+red[7];
        float mu  = S * (1.f/16384.f);
        float var = SS * (1.f/16384.f) - mu*mu;
        stats[bg*2]   = mu;
        stats[bg*2+1] = rsqrtf(var + 1e-5f);
    }
}

// ---------------- K1b: normalize -> d_out (fp32) + x tokens (bf16 [B,N,C]) ----------------
__global__ void __launch_bounds__(256) gn_apply(const float* __restrict__ in,
                                                const float* __restrict__ gw,
                                                const float* __restrict__ gb,
                                                const float* __restrict__ stats,
                                                float* __restrict__ normed,
                                                bf16_t* __restrict__ x) {
    int b  = blockIdx.x >> 6;
    int p0 = (blockIdx.x & 63) << 6;
    int tid = threadIdx.x;
    __shared__ bf16_t tile[64 * 130];
    for (int i = tid; i < 8192; i += 256) {
        int c = i >> 6, p = i & 63;
        size_t idx = ((size_t)(b*CC + c)) * NN + p0 + p;
        float v = in[idx];
        int sg = b*32 + (c >> 2);
        float xn = (v - stats[sg*2]) * stats[sg*2+1] * gw[c] + gb[c];
        normed[idx] = xn;
        tile[p*130 + c] = (bf16_t)xn;
    }
    __syncthreads();
    bf16_t* xb = x + ((size_t)(b*NN + p0)) * CC;
    for (int i = tid; i < 4096; i += 256) {
        int p = i >> 6, cp = i & 63;
        unsigned int d = *(const unsigned int*)&tile[p*130 + cp*2];
        *(unsigned int*)&xb[p*CC + cp*2] = d;
    }
}

// ---------------- K2: phase-parallel qkv. grid 768: ph = blk>>8 ----------------
// q plain+scaled; k XOR-swizzled; vT transposed + bit2<->3 j-perm + XOR-swizzled.
__global__ void __launch_bounds__(256) qkv_gemm(const bf16_t* __restrict__ x,
        const float* __restrict__ Wq, const float* __restrict__ bq,
        const float* __restrict__ Wk, const float* __restrict__ bk,
        const float* __restrict__ Wv, const float* __restrict__ bv,
        bf16_t* __restrict__ q, bf16_t* __restrict__ k, bf16_t* __restrict__ vT) {
    __shared__ bf16_t wb[CC * LDP];
    const int ph  = blockIdx.x >> 8;
    const int blk = blockIdx.x & 255;
    int b  = blk >> 5;
    int n0 = (blk & 31) << 7;
    int tid = threadIdx.x;
    int lane = tid & 63, l15 = lane & 15, quad = lane >> 4;
    int w = tid >> 6;
    bf16x8 afr[2][4];
    #pragma unroll
    for (int rt = 0; rt < 2; rt++)
        #pragma unroll
        for (int kb = 0; kb < 4; kb++)
            afr[rt][kb] = *(const bf16x8*)&x[(size_t)(b*NN + n0 + w*32 + rt*16 + l15)*CC + kb*32 + quad*8];

    const float* W  = (ph == 0) ? Wq : (ph == 1 ? Wk : Wv);
    const float* bs = (ph == 0) ? bq : (ph == 1 ? bk : bv);
    for (int i = tid; i < 2048; i += 256) {
        int row = i >> 4, s8 = i & 15;
        const float* wp = W + row*128 + s8*8;
        bf16x8 v;
        #pragma unroll
        for (int j = 0; j < 8; j++) v[j] = (bf16_t)wp[j];
        *(bf16x8*)&wb[row*LDP + s8*8] = v;
    }
    __syncthreads();
    f32x4 acc[2][8];
    f32x4 z = {0.f, 0.f, 0.f, 0.f};
    #pragma unroll
    for (int rt = 0; rt < 2; rt++)
        #pragma unroll
        for (int t = 0; t < 8; t++) acc[rt][t] = z;
    #pragma unroll
    for (int kb = 0; kb < 4; kb++)
        #pragma unroll
        for (int t = 0; t < 8; t++) {
            bf16x8 bf = *(const bf16x8*)&wb[(t*16 + l15)*LDP + kb*32 + quad*8];
            acc[0][t] = mfma16(afr[0][kb], bf, acc[0][t]);
            acc[1][t] = mfma16(afr[1][kb], bf, acc[1][t]);
        }
    __syncthreads();   // all waves done reading W from wb
    if (ph < 2) {
        float sc = (ph == 0) ? SCALE2 : 1.0f;
        #pragma unroll
        for (int t = 0; t < 8; t++) {
            float bias = bs[t*16 + l15];
            #pragma unroll
            for (int rt = 0; rt < 2; rt++)
                #pragma unroll
                for (int r = 0; r < 4; r++) {
                    int nloc = w*32 + rt*16 + quad*4 + r;
                    wb[nloc*LDP + t*16 + l15] = (bf16_t)((acc[rt][t][r] + bias) * sc);
                }
        }
        __syncthreads();
        bf16_t* outp = (ph == 0) ? q : k;
        for (int i = tid; i < 2048; i += 256) {
            int row = i >> 4, g = i & 15;
            bf16x8 vv = *(const bf16x8*)&wb[row*LDP + g*8];
            int gd = (ph == 0) ? g : (g ^ (row & 15));
            *(bf16x8*)&outp[(size_t)(b*NN + n0 + row)*CC + gd*8] = vv;
        }
    } else {
        #pragma unroll
        for (int t = 0; t < 8; t++) {
            float bias = bs[t*16 + l15];
            #pragma unroll
            for (int rt = 0; rt < 2; rt++)
                #pragma unroll
                for (int r = 0; r < 4; r++) {
                    int nloc = w*32 + rt*16 + quad*4 + r;   // vT transpose: [c][nloc]
                    wb[(t*16 + l15)*LDP + nloc] = (bf16_t)(acc[rt][t][r] + bias);
                }
        }
        __syncthreads();
        for (int i = tid; i < 8192; i += 256) {
            int c = i >> 6, np = i & 63;   // np = pair index (n = 2*np)
            unsigned int d = *(const unsigned int*)&wb[c*LDP + np*2];
            // bit2<->3 swap of n == bit1<->2 swap of np (PV B-frag identity perm)
            int npp = (np & ~6) | ((np & 2) << 1) | ((np & 4) >> 1);
            int g = (npp >> 2) ^ (c & 15);            // XOR bank swizzle on 8-elem groups
            *(unsigned int*)&vT[(size_t)(b*CC + c)*NN + n0 + (g << 3) + ((npp & 3) << 1)] = d;
        }
    }
}

// ---------------- K3: flash, 512 thr / 8 waves (2 waves/SIMD), 32 q-rows/wave ----------------
// grid 256: b = blk>>5, qb = (blk>>1)&15 (256 q-rows), jh = blk&1 (2048 j).
// Maxless tt-streamed softmax. Partials: packed bf16 pairs opd[jh][b][cpair][q] + l in mlf.
__global__ void __launch_bounds__(512, 2) flash_attn(const bf16_t* __restrict__ qg_,
                                                     const bf16_t* __restrict__ kg,
                                                     const bf16_t* __restrict__ vg,
                                                     unsigned* __restrict__ opd,
                                                     float* __restrict__ mlf) {
    __shared__ bf16_t kbuf[2][128*128];   // 64 KB
    __shared__ bf16_t vbuf[2][128*128];   // 64 KB
    const int b    = blockIdx.x >> 5;
    const int qb   = (blockIdx.x >> 1) & 15;
    const int jh   = blockIdx.x & 1;
    const int q0   = qb << 8;
    const int j00  = jh << 11;
    const int tid  = threadIdx.x;
    const int lane = tid & 63;
    const int l31  = lane & 31;
    const int h    = lane >> 5;
    const int w    = tid >> 6;            // 0..7

    // 32 q-rows per wave; q frags resident (32 VGPRs)
    bf16x8 qf[8];
    {
        const bf16_t* qr = qg_ + ((size_t)(b*NN + q0 + w*32 + l31))*CC + h*8;
        #pragma unroll
        for (int kc = 0; kc < 8; kc++) qf[kc] = *(const bf16x8*)(qr + kc*16);
    }
    int gofs[8];
    #pragma unroll
    for (int kc = 0; kc < 8; kc++) gofs[kc] = ((2*kc + h) ^ (l31 & 15)) << 3;

    f32x16 ot[4];
    #pragma unroll
    for (int ct = 0; ct < 4; ct++)
        #pragma unroll
        for (int r = 0; r < 16; r++) ot[ct][r] = 0.f;
    float l = 0.f;

    // stage tile 0: K-tile 2048 16B-chunks, V-tile 2048 chunks; 512 threads x 4 each
    {
        const bf16_t* kt = kg + ((size_t)(b*NN + j00))*CC;
        #pragma unroll
        for (int it = 0; it < 4; it++) {
            int cb = it*512 + tid;
            gld16(kt + (size_t)cb*8, &kbuf[0][cb*8]);
        }
        #pragma unroll
        for (int it = 0; it < 4; it++) {
            int c = it*512 + tid;
            gld16(vg + ((size_t)(b*CC + (c >> 4)))*NN + j00 + (c & 15)*8, &vbuf[0][c*8]);
        }
    }
    __syncthreads();

    for (int i = 0; i < 16; i++) {
        const int cur = i & 1;
        if (i < 15) {                      // prefetch next tile (drained by end barrier)
            const int j0n = j00 + ((i + 1) << 7);
            const bf16_t* kt = kg + ((size_t)(b*NN + j0n))*CC;
            #pragma unroll
            for (int it = 0; it < 4; it++) {
                int cb = it*512 + tid;
                gld16(kt + (size_t)cb*8, &kbuf[cur^1][cb*8]);
            }
            #pragma unroll
            for (int it = 0; it < 4; it++) {
                int c = it*512 + tid;
                gld16(vg + ((size_t)(b*CC + (c >> 4)))*NN + j0n + (c & 15)*8, &vbuf[cur^1][c*8]);
            }
        }
        #pragma unroll
        for (int tt = 0; tt < 4; tt++) {
            // S^T chunk (32 j-rows x 32 q-rows)
            f32x16 st;
            #pragma unroll
            for (int r = 0; r < 16; r++) st[r] = 0.f;
            const bf16_t* krow = &kbuf[cur][(tt*32 + l31)*128];
            #pragma unroll
            for (int kc = 0; kc < 8; kc++) {
                bf16x8 kf = *(const bf16x8*)(krow + gofs[kc]);
                st = mfma32(kf, qf[kc], st);
            }
            // maxless softmax: independent exp2, tree sum, pack
            #pragma unroll
            for (int r = 0; r < 16; r++) st[r] = __builtin_amdgcn_exp2f(st[r]);
            {
                float a0 = (st[0]+st[1]) + (st[2]+st[3]);
                float a1 = (st[4]+st[5]) + (st[6]+st[7]);
                float a2 = (st[8]+st[9]) + (st[10]+st[11]);
                float a3 = (st[12]+st[13]) + (st[14]+st[15]);
                l += (a0 + a1) + (a2 + a3);
            }
            union { unsigned u[4]; bf16x8 v; } pf[2];
            #pragma unroll
            for (int kcl = 0; kcl < 2; kcl++)
                #pragma unroll
                for (int g = 0; g < 4; g++)
                    pf[kcl].u[g] = pack2bf(st[8*kcl + 2*g], st[8*kcl + 2*g + 1]);
            // PV for this j-chunk; pure accumulate (no rescale)
            #pragma unroll
            for (int kcl = 0; kcl < 2; kcl++) {
                const int kc = tt*2 + kcl;
                #pragma unroll
                for (int ct = 0; ct < 4; ct++) {
                    bf16x8 vf = *(const bf16x8*)&vbuf[cur][(ct*32 + l31)*128 + gofs[kc]];
                    ot[ct] = mfma32(vf, pf[kcl].v, ot[ct]);
                }
            }
        }
        __syncthreads();
    }
    // epilogue: combine lane^32 halves of l; store packed bf16 partials [cpair][q]
    l += __shfl_xor(l, 32, 64);
    const int row0 = q0 + w*32 + l31;
    unsigned* ob = opd + ((size_t)(jh*BB + b)) * 64 * NN;
    #pragma unroll
    for (int ct = 0; ct < 4; ct++)
        #pragma unroll
        for (int rp = 0; rp < 8; rp++) {
            int cpair = ct*16 + (rp & 1) + 4*(rp >> 1) + 2*h;
            ob[(size_t)cpair*NN + row0] = pack2bf(ot[ct][2*rp], ot[ct][2*rp + 1]);
        }
    if (h == 0)
        mlf[((size_t)(jh*BB + b))*NN + row0] = l;
}

// ---------------- K3b: merge 2 j-half partials (plain sums) -> ao (bf16 [B,N,C]) ----------------
__global__ void __launch_bounds__(256) merge_attn(const unsigned* __restrict__ opd,
                                                  const float* __restrict__ mlf,
                                                  bf16_t* __restrict__ ao) {
    __shared__ float inv[128];
    __shared__ unsigned tile[128 * 65];
    const int b  = blockIdx.x >> 5;
    const int q0 = (blockIdx.x & 31) << 7;
    const int tid = threadIdx.x;
    if (tid < 128) {
        float lt = 0.f;
        #pragma unroll
        for (int p = 0; p < 2; p++) lt += mlf[((size_t)(p*BB + b))*NN + q0 + tid];
        inv[tid] = 1.0f / lt;
    }
    __syncthreads();
    for (int i = tid; i < 8192; i += 256) {
        int q = i & 127, cp = i >> 7;
        float lo = 0.f, hi = 0.f;
        #pragma unroll
        for (int p = 0; p < 2; p++) {
            unsigned u = opd[(((size_t)(p*BB + b))*64 + cp)*NN + q0 + q];
            union { unsigned u; float f; } a, c;
            a.u = u << 16; c.u = u & 0xffff0000u;
            lo += a.f; hi += c.f;
        }
        float s = inv[q];
        tile[q*65 + cp] = pack2bf(lo * s, hi * s);
    }
    __syncthreads();
    unsigned* aod = (unsigned*)ao;
    for (int i = tid; i < 8192; i += 256) {
        int q = i >> 6, cp = i & 63;
        aod[((size_t)(b*NN + q0 + q))*64 + cp] = tile[q*65 + cp];
    }
}

// ---------------- K4: proj GEMM + bias + transpose + residual into d_out ----------------
__global__ void __launch_bounds__(256) proj_out(const bf16_t* __restrict__ ao,
                                                const float* __restrict__ Wp,
                                                const float* __restrict__ bp,
                                                float* __restrict__ out) {
    __shared__ bf16_t wb[CC * LDP];
    int b  = blockIdx.x >> 5;
    int n0 = (blockIdx.x & 31) << 7;
    int tid = threadIdx.x;
    int lane = tid & 63, l15 = lane & 15, quad = lane >> 4;
    int w = tid >> 6;
    bf16x8 afr[2][4];
    #pragma unroll
    for (int rt = 0; rt < 2; rt++)
        #pragma unroll
        for (int kb = 0; kb < 4; kb++)
            afr[rt][kb] = *(const bf16x8*)&ao[(size_t)(b*NN + n0 + w*32 + rt*16 + l15)*CC + kb*32 + quad*8];
    for (int i = tid; i < 2048; i += 256) {
        int row = i >> 4, s8 = i & 15;
        const float* wp = Wp + row*128 + s8*8;
        bf16x8 v;
        #pragma unroll
        for (int j = 0; j < 8; j++) v[j] = (bf16_t)wp[j];
        *(bf16x8*)&wb[row*LDP + s8*8] = v;
    }
    __syncthreads();
    f32x4 acc[2][8];
    f32x4 z = {0.f, 0.f, 0.f, 0.f};
    #pragma unroll
    for (int rt = 0; rt < 2; rt++)
        #pragma unroll
        for (int t = 0; t < 8; t++) acc[rt][t] = z;
    #pragma unroll
    for (int kb = 0; kb < 4; kb++)
        #pragma unroll
        for (int t = 0; t < 8; t++) {
            bf16x8 bf = *(const bf16x8*)&wb[(t*16 + l15)*LDP + kb*32 + quad*8];
            acc[0][t] = mfma16(afr[0][kb], bf, acc[0][t]);
            acc[1][t] = mfma16(afr[1][kb], bf, acc[1][t]);
        }
    __syncthreads();
    #pragma unroll
    for (int t = 0; t < 8; t++) {
        float bias = bp[t*16 + l15];
        #pragma unroll
        for (int rt = 0; rt < 2; rt++)
            #pragma unroll
            for (int r = 0; r < 4; r++) {
                int nloc = w*32 + rt*16 + quad*4 + r;
                wb[(t*16 + l15)*LDP + nloc] = (bf16_t)(acc[rt][t][r] + bias);
            }
    }
    __syncthreads();
    for (int i = tid; i < 8192; i += 256) {
        int c = i >> 6, np = i & 63;
        bf16_t b0 = wb[c*LDP + np*2], b1 = wb[c*LDP + np*2 + 1];
        size_t idx = (size_t)(b*CC + c)*NN + n0 + np*2;
        float2 nv = *(float2*)&out[idx];
        nv.x += (float)b0;
        nv.y += (float)b1;
        *(float2*)&out[idx] = nv;
    }
}

extern "C" void kernel_launch(void* const* d_in, const int* in_sizes, int n_in,
                              void* d_out, int out_size, void* d_ws, size_t ws_size,
                              hipStream_t stream) {
    const float* in = (const float*)d_in[0];
    const float* gw = (const float*)d_in[1];
    const float* gb = (const float*)d_in[2];
    const float* Wq = (const float*)d_in[3];
    const float* bq = (const float*)d_in[4];
    const float* Wk = (const float*)d_in[5];
    const float* bk = (const float*)d_in[6];
    const float* Wv = (const float*)d_in[7];
    const float* bv = (const float*)d_in[8];
    const float* Wp = (const float*)d_in[9];
    const float* bp = (const float*)d_in[10];
    float* out = (float*)d_out;

    char* ws = (char*)d_ws;
    const size_t SZ = (size_t)BB * NN * CC * 2;        // 8.39 MB
    float*    stats = (float*)ws;
    bf16_t*   x  = (bf16_t*)(ws + 2048);
    bf16_t*   q  = (bf16_t*)(ws + 2048 + SZ);
    bf16_t*   kk = (bf16_t*)(ws + 2048 + 2*SZ);
    bf16_t*   vT = (bf16_t*)(ws + 2048 + 3*SZ);
    bf16_t*   ao = (bf16_t*)(ws + 2048 + 4*SZ);
    unsigned* op = (unsigned*)(ws + 2048 + 5*SZ);      // 16.78 MB packed-bf16 partials
    float*    ml = (float*)(ws + 2048 + 5*SZ + (size_t)2*BB*64*NN*4);

    gn_stats  <<<256, 256, 0, stream>>>(in, stats);
    gn_apply  <<<512, 256, 0, stream>>>(in, gw, gb, stats, out, x);
    qkv_gemm  <<<768, 256, 0, stream>>>(x, Wq, bq, Wk, bk, Wv, bv, q, kk, vT);
    flash_attn<<<256, 512, 0, stream>>>(q, kk, vT, op, ml);
    merge_attn<<<256, 256, 0, stream>>>(op, ml, ao);
    proj_out  <<<256, 256, 0, stream>>>(ao, Wp, bp, out);
}